// Round 3
// 898.260 us; speedup vs baseline: 1.5719x; 1.5719x over previous
//
#include <hip/hip_runtime.h>

// SemiseparableLayer on MI355X (gfx950) — v4: v1 (verified, 1412us) + latency fixes only.
// All data paths (layouts, staging, MFMA orientation, transposes, K2) are v1 VERBATIM.
// Changes, each provably data-path-neutral:
//  1. Rolled loops (#pragma unroll 2) — kills L1I thrash from v1's full unroll. The ypk[64]
//     register array that forced the unroll is replaced by writing the causal partial y
//     (bf16-packed, bit-identical arithmetic to v1) into `out`, RMW'd by the anticausal
//     pass (same thread). DT=1 keeps full fp32 partials in out (strictly more accurate).
//  2. ONE __syncthreads per stage (was 2): the twr/trd T-plane is per-wave (lgkmcnt
//     ordering suffices); the single remaining barrier guards the matrix double-buffer.
//  3. u-row raw-prefetch one stage ahead (pure hoist of v1's ldu loads; OOB-guarded).
//  4. __launch_bounds__(256,4); DT=0 drops the (dead) lo matrix planes from LDS
//     (k3: 29.7->21.5 KB, k1: ~50->34.8 KB) -> 4 blocks/CU.
//  5. Wave-parallel k_detect (v1: 512 serial loads on one thread).
//
// ws: [0] int flag; +1024 Sc[16][4128][32] f32; Sa same. (= v1's 16.9 MB layout)

#define BATCH 4096
#define NCH   16
#define CHS   32
#define SROWS (BATCH + 32)
#define TSTR  36

typedef __attribute__((ext_vector_type(8))) short short8;
typedef __attribute__((ext_vector_type(4))) float f32x4;
typedef short8 __attribute__((may_alias)) short8a;
typedef f32x4 __attribute__((may_alias)) f32x4a;
typedef unsigned __attribute__((may_alias)) uinta;

#define MFMA16(a, b, c) __builtin_amdgcn_mfma_f32_16x16x32_bf16(a, b, c, 0, 0, 0)

__device__ __forceinline__ unsigned short bf16u(float x) {
  unsigned u = __builtin_bit_cast(unsigned, x);
  u += 0x7fffu + ((u >> 16) & 1u);
  return (unsigned short)(u >> 16);
}
__device__ __forceinline__ float bf2f(unsigned short u) {
  return __builtin_bit_cast(float, ((unsigned)u) << 16);
}
template <int DT>
__device__ __forceinline__ const void* eptr(const void* b, long e) {
  return (const char*)b + e * (DT ? 4 : 2);
}

// stage matrix -> LDS hi(+lo) bf16 planes, padded stride PSTR (shorts). v1 verbatim.
template <int DT, int ROWS, int COLS, int PSTR>
__device__ __forceinline__ void stage2(const void* gp, short* hi, short* lo, int tid) {
  if constexpr (DT == 0) {
    const uinta* gu = (const uinta*)gp;
    for (int i = tid; i < ROWS * COLS / 2; i += 256) {
      int r = i / (COLS / 2), c = i - r * (COLS / 2);
      ((uinta*)(hi + r * PSTR))[c] = gu[i];
    }
  } else {
    const float* gf = (const float*)gp;
    for (int i = tid; i < ROWS * COLS; i += 256) {
      int r = i / COLS, c = i - r * COLS;
      float v = gf[i];
      unsigned short h = bf16u(v);
      hi[r * PSTR + c] = (short)h;
      lo[r * PSTR + c] = (short)bf16u(v - bf2f(h));
    }
  }
}
// hi-only variant (output matrices C, D, G). v1 verbatim.
template <int DT, int ROWS, int COLS, int PSTR>
__device__ __forceinline__ void stage1(const void* gp, short* hi, int tid) {
  if constexpr (DT == 0) {
    const uinta* gu = (const uinta*)gp;
    for (int i = tid; i < ROWS * COLS / 2; i += 256) {
      int r = i / (COLS / 2), c = i - r * (COLS / 2);
      ((uinta*)(hi + r * PSTR))[c] = gu[i];
    }
  } else {
    const float* gf = (const float*)gp;
    for (int i = tid; i < ROWS * COLS; i += 256) {
      int r = i / COLS, c = i - r * COLS;
      hi[r * PSTR + c] = (short)bf16u(gf[i]);
    }
  }
}

// B-operand fragment of 32-col matrix stored [n][k] stride 40: B[k][n] = M[n][k]. v1 verbatim.
__device__ __forceinline__ short8 ldfrag32(const short* l, int lane, int nbase) {
  int n = nbase + (lane & 15), q = lane >> 4;
  return *(const short8a*)(l + n * 40 + q * 8);
}
// B-operand fragment of 16-col matrix stride 24; rows k>=16 zero. v1 verbatim.
__device__ __forceinline__ short8 ldfrag16(const short* l, int lane, int nbase) {
  int n = nbase + (lane & 15), q = lane >> 4;
  short8 z = {};
  if (q < 2) z = *(const short8a*)(l + n * 24 + q * 8);
  return z;
}

// fp32 C-layout (col=lane&15,row=quad*4+r) -> fp32 plane [16][TSTR]. v1 verbatim.
__device__ __forceinline__ void twr(const f32x4* acc, float* T, int lane) {
  const int c = lane & 15, q = lane >> 4;
#pragma unroll
  for (int h = 0; h < 2; ++h)
#pragma unroll
    for (int r = 0; r < 4; ++r) T[(q * 4 + r) * TSTR + h * 16 + c] = acc[h][r];
}
// plane -> A-frag (A[m=lane&15][k=quad*8+j]) with reader-side hi/lo split. v1 verbatim.
__device__ __forceinline__ void trd(const float* T, int lane, short8& hi, short8& lo) {
  const int m = lane & 15, q = lane >> 4;
  const float* p = T + m * TSTR + q * 8;
#pragma unroll
  for (int j = 0; j < 8; ++j) {
    float v = p[j];
    unsigned short h = bf16u(v);
    hi[j] = (short)h;
    lo[j] = (short)bf16u(v - bf2f(h));
  }
}

// u-row raw load (prefetchable) + convert; DT=1 convert identical to v1's ldu.
template <int DT> struct URaw;
template <> struct URaw<0> { short8 s; };
template <> struct URaw<1> { f32x4 a, b; };

template <int DT>
__device__ __forceinline__ URaw<DT> ldu_raw(const void* U, size_t off) {
  URaw<DT> r;
  if constexpr (DT == 0) {
    r.s = *(const short8a*)((const short*)U + off);
  } else {
    const f32x4a* p = (const f32x4a*)((const float*)U + off);
    r.a = p[0];
    r.b = p[1];
  }
  return r;
}
template <int DT>
__device__ __forceinline__ void u_cvt(const URaw<DT>& r, short8& uhi, short8& ulo) {
  if constexpr (DT == 0) {
    uhi = r.s;
    ulo = short8{};
  } else {
#pragma unroll
    for (int j = 0; j < 4; ++j) {
      float v = r.a[j];
      unsigned short h = bf16u(v);
      uhi[j] = (short)h;
      ulo[j] = (short)bf16u(v - bf2f(h));
    }
#pragma unroll
    for (int j = 0; j < 4; ++j) {
      float v = r.b[j];
      unsigned short h = bf16u(v);
      uhi[4 + j] = (short)h;
      ulo[4 + j] = (short)bf16u(v - bf2f(h));
    }
  }
}
template <int DT>
__device__ __forceinline__ float ldbias(const void* b, int i) {
  if constexpr (DT == 0) return bf2f((unsigned short)((const short*)b)[i]);
  else return ((const float*)b)[i];
}

// one state update: out = (Xhi+Xlo)@M^T + u@B^T (fp32 arm adds lo-matrix terms). v1 verbatim.
template <int DT>
__device__ __forceinline__ void step_state(const short8& Xhi, const short8& Xlo,
                                           const short8& uhi, const short8& ulo,
                                           const short* Mhi, const short* Mlo,
                                           const short* Bhi, const short* Blo,
                                           f32x4* out, int lane) {
#pragma unroll
  for (int h = 0; h < 2; ++h) {
    const f32x4 z4 = {0.f, 0.f, 0.f, 0.f};
    short8 bA = ldfrag32(Mhi, lane, h * 16);
    f32x4 ax = MFMA16(Xhi, bA, z4);
    ax = MFMA16(Xlo, bA, ax);
    short8 bB = ldfrag16(Bhi, lane, h * 16);
    ax = MFMA16(uhi, bB, ax);
    if constexpr (DT) {
      short8 bAl = ldfrag32(Mlo, lane, h * 16);
      ax = MFMA16(Xhi, bAl, ax);
      ax = MFMA16(ulo, bB, ax);
      short8 bBl = ldfrag16(Blo, lane, h * 16);
      ax = MFMA16(uhi, bBl, ax);
    }
    out[h] = ax;
  }
}

// ---------------- dtype detector (wave-parallel) ----------------
__global__ void k_detect(const unsigned short* __restrict__ U16, int* __restrict__ flag) {
  int lane = threadIdx.x;
  int bad = 0;
  for (int i = lane; i < 512; i += 64) {
    int e = (U16[i] >> 7) & 0xFF;
    bad += ((e > 134) || (e < 96 && e != 0)) ? 1 : 0;
  }
#pragma unroll
  for (int s = 32; s; s >>= 1) bad += __shfl_xor(bad, s);
  if (lane == 0) *flag = (bad > 48) ? 1 : 0;
}

// ---------------- K1: chunk-local scans from zero (+ identity tile -> P^T) ----------
template <int DT>
__global__ __launch_bounds__(256, 4) void k1_scan(
    const int* __restrict__ flagp, const void* __restrict__ U,
    const void* __restrict__ Am, const void* __restrict__ Bm,
    const void* __restrict__ Em, const void* __restrict__ Fm,
    float* __restrict__ Sc, float* __restrict__ Sa) {
  if (*flagp != DT) return;
  const int ch = blockIdx.x, tile = blockIdx.y;
  const bool ident = (tile == 64);
  const int tid = threadIdx.x, lane = tid & 63, w = tid >> 6;
  const int s = ch * CHS;
  constexpr int NP = DT ? 2 : 1;  // lo planes are dead for DT=0 (v1 never wrote/read them)
  __shared__ __align__(16) short mA[2][NP][1280];
  __shared__ __align__(16) short mB[2][NP][768];
  __shared__ __align__(16) short mE[2][NP][1280];
  __shared__ __align__(16) short mF[2][NP][768];
  __shared__ __align__(16) float T[4][2][16 * TSTR];

  short8 Xhi = {}, Xlo = {}, Zhi = {}, Zlo = {};
  if (ident) {
    const int m = lane & 15, q = lane >> 4;
    short8 id = {};
#pragma unroll
    for (int j = 0; j < 8; ++j) id[j] = ((q * 8 + j) == (w * 16 + m)) ? (short)0x3F80 : (short)0;
    Xhi = id; Zhi = id;
  }

  stage2<DT, 32, 32, 40>(eptr<DT>(Am, (long)s * 1024), mA[0][0], mA[0][NP - 1], tid);
  stage2<DT, 32, 16, 24>(eptr<DT>(Bm, (long)s * 512), mB[0][0], mB[0][NP - 1], tid);
  stage2<DT, 32, 32, 40>(eptr<DT>(Em, (long)(s + CHS - 1) * 1024), mE[0][0], mE[0][NP - 1], tid);
  stage2<DT, 32, 16, 24>(eptr<DT>(Fm, (long)(s + CHS - 1) * 512), mF[0][0], mF[0][NP - 1], tid);

  const size_t urow = (size_t)(ident ? 0 : (tile * 64 + w * 16 + (lane & 15))) * 8192;
  const int qq = (lane >> 4) & 1;
  URaw<DT> unc{}, una{};
  if (!ident) {
    unc = ldu_raw<DT>(U, urow + (size_t)s * 16 + qq * 8);
    una = ldu_raw<DT>(U, urow + (size_t)(s + CHS - 1) * 16 + qq * 8);
  }
  __syncthreads();

  f32x4 aX[2], aZ[2];
#pragma unroll 2
  for (int t = 0; t < CHS; ++t) {
    const int kc = s + t, ka = s + CHS - 1 - t, buf = t & 1;
    if (t < CHS - 1) {
      stage2<DT, 32, 32, 40>(eptr<DT>(Am, (long)(kc + 1) * 1024), mA[buf ^ 1][0], mA[buf ^ 1][NP - 1], tid);
      stage2<DT, 32, 16, 24>(eptr<DT>(Bm, (long)(kc + 1) * 512), mB[buf ^ 1][0], mB[buf ^ 1][NP - 1], tid);
      stage2<DT, 32, 32, 40>(eptr<DT>(Em, (long)(ka - 1) * 1024), mE[buf ^ 1][0], mE[buf ^ 1][NP - 1], tid);
      stage2<DT, 32, 16, 24>(eptr<DT>(Fm, (long)(ka - 1) * 512), mF[buf ^ 1][0], mF[buf ^ 1][NP - 1], tid);
    }
    short8 uch = {}, ucl = {}, uah = {}, ual = {};
    if (!ident) {
      u_cvt<DT>(unc, uch, ucl);
      u_cvt<DT>(una, uah, ual);
      if (t < CHS - 1) {
        unc = ldu_raw<DT>(U, urow + (size_t)(kc + 1) * 16 + qq * 8);
        una = ldu_raw<DT>(U, urow + (size_t)(ka - 1) * 16 + qq * 8);
      }
    }
    step_state<DT>(Xhi, Xlo, uch, ucl, mA[buf][0], mA[buf][NP - 1], mB[buf][0], mB[buf][NP - 1], aX, lane);
    step_state<DT>(Zhi, Zlo, uah, ual, mE[buf][0], mE[buf][NP - 1], mF[buf][0], mF[buf][NP - 1], aZ, lane);
    twr(aX, T[w][0], lane);
    twr(aZ, T[w][1], lane);
    trd(T[w][0], lane, Xhi, Xlo);   // same-wave T round trip: lgkmcnt suffices, no barrier
    trd(T[w][1], lane, Zhi, Zlo);
    __syncthreads();                // guards the matrix double-buffer only
  }

  if (!ident || w < 2) {
    const int grow = tile * 64 + w * 16;
#pragma unroll
    for (int h = 0; h < 2; ++h)
#pragma unroll
      for (int r = 0; r < 4; ++r) {
        const int m = (lane >> 4) * 4 + r, col = h * 16 + (lane & 15);
        const size_t off = ((size_t)ch * SROWS + grow + m) * 32 + col;
        Sc[off] = aX[h][r];
        Sa[off] = aZ[h][r];
      }
  }
}

// ---------------- K2: sequential fp32 combine over chunks (v1 verbatim) ----------------
__global__ __launch_bounds__(256) void k2_comb(float* __restrict__ Sc, float* __restrict__ Sa) {
  const int dir = blockIdx.y;
  const int r = threadIdx.x >> 5, j = threadIdx.x & 31;
  const int row = blockIdx.x * 8 + r;
  float* S = dir ? Sa : Sc;
  __shared__ float P[32][33];
  __shared__ float xs[8][33];
  float x = 0.f;
  for (int it = 0; it < NCH; ++it) {
    const int ch = dir ? (NCH - 1 - it) : it;
    const size_t base = ((size_t)ch * SROWS + row) * 32 + j;
    const float s_local = S[base];
    for (int i = threadIdx.x; i < 1024; i += 256)
      P[i >> 5][i & 31] = S[((size_t)ch * SROWS + BATCH + (i >> 5)) * 32 + (i & 31)];
    xs[r][j] = x;
    __syncthreads();
    S[base] = x;
    float acc = s_local;
#pragma unroll
    for (int m = 0; m < 32; ++m) acc += xs[r][m] * P[m][j];
    x = acc;
    __syncthreads();
  }
}

// ---------------- K3: re-scan with true entry states, produce y ----------------
template <int DT>
__global__ __launch_bounds__(256, 4) void k3_scan(
    const int* __restrict__ flagp, const void* __restrict__ U,
    const void* __restrict__ Am, const void* __restrict__ Bm,
    const void* __restrict__ Cm, const void* __restrict__ Dm,
    const void* __restrict__ Em, const void* __restrict__ Fm,
    const void* __restrict__ Gm, const void* __restrict__ biasv,
    const float* __restrict__ xin, const float* __restrict__ zin,
    void* __restrict__ out) {
  if (*flagp != DT) return;
  const int ch = blockIdx.x, tile = blockIdx.y;
  const int tid = threadIdx.x, lane = tid & 63, w = tid >> 6;
  const int s = ch * CHS;
  constexpr int NP = DT ? 2 : 1;
  __shared__ __align__(16) short sA[2][NP][1280];
  __shared__ __align__(16) short sB[2][NP][768];
  __shared__ __align__(16) short sC[2][640];
  __shared__ __align__(16) short sD[2][384];
  __shared__ __align__(16) float T[4][16 * TSTR];
  const int cidx = lane & 15, quad = lane >> 4, qq = quad & 1;
  const size_t urow = (size_t)(tile * 64 + w * 16 + cidx) * 8192;

  // ---- causal phase ----
  short8 Xhi, Xlo;
  {
    const float* xp = xin + ((size_t)ch * SROWS + tile * 64 + w * 16 + cidx) * 32 + quad * 8;
#pragma unroll
    for (int j = 0; j < 8; ++j) {
      float v = xp[j];
      unsigned short h = bf16u(v);
      Xhi[j] = (short)h;
      Xlo[j] = (short)bf16u(v - bf2f(h));
    }
  }
  stage2<DT, 32, 32, 40>(eptr<DT>(Am, (long)s * 1024), sA[0][0], sA[0][NP - 1], tid);
  stage2<DT, 32, 16, 24>(eptr<DT>(Bm, (long)s * 512), sB[0][0], sB[0][NP - 1], tid);
  stage1<DT, 16, 32, 40>(eptr<DT>(Cm, (long)s * 512), sC[0], tid);
  stage1<DT, 16, 16, 24>(eptr<DT>(Dm, (long)s * 256), sD[0], tid);
  URaw<DT> un = ldu_raw<DT>(U, urow + (size_t)s * 16 + qq * 8);
  __syncthreads();

  f32x4 aX[2];
#pragma unroll 2
  for (int t = 0; t < CHS; ++t) {
    const int k = s + t, buf = t & 1;
    if (t < CHS - 1) {
      stage2<DT, 32, 32, 40>(eptr<DT>(Am, (long)(k + 1) * 1024), sA[buf ^ 1][0], sA[buf ^ 1][NP - 1], tid);
      stage2<DT, 32, 16, 24>(eptr<DT>(Bm, (long)(k + 1) * 512), sB[buf ^ 1][0], sB[buf ^ 1][NP - 1], tid);
      stage1<DT, 16, 32, 40>(eptr<DT>(Cm, (long)(k + 1) * 512), sC[buf ^ 1], tid);
      stage1<DT, 16, 16, 24>(eptr<DT>(Dm, (long)(k + 1) * 256), sD[buf ^ 1], tid);
    }
    short8 uh, ul;
    u_cvt<DT>(un, uh, ul);
    if (t < CHS - 1) un = ldu_raw<DT>(U, urow + (size_t)(k + 1) * 16 + qq * 8);
    const f32x4 z4 = {0.f, 0.f, 0.f, 0.f};
    const short8 cf = ldfrag32(sC[buf], lane, 0);
    f32x4 ya = MFMA16(Xhi, cf, z4);
    ya = MFMA16(Xlo, cf, ya);
    const short8 df = ldfrag16(sD[buf], lane, 0);
    ya = MFMA16(uh, df, ya);
    if constexpr (DT) ya = MFMA16(ul, df, ya);
    const float bv = ldbias<DT>(biasv, k * 16 + cidx);
    {  // causal partial y -> out (bit-identical to v1's ypk register path for DT=0)
      const size_t obase = (size_t)(tile * 64 + w * 16 + quad * 4) * 8192 + (size_t)k * 16 + cidx;
      if constexpr (DT == 0) {
        short* o = (short*)out;
#pragma unroll
        for (int r = 0; r < 4; ++r) o[obase + (size_t)r * 8192] = (short)bf16u(ya[r] + bv);
      } else {
        float* o = (float*)out;
#pragma unroll
        for (int r = 0; r < 4; ++r) o[obase + (size_t)r * 8192] = ya[r] + bv;
      }
    }
    step_state<DT>(Xhi, Xlo, uh, ul, sA[buf][0], sA[buf][NP - 1], sB[buf][0], sB[buf][NP - 1], aX, lane);
    twr(aX, T[w], lane);
    trd(T[w], lane, Xhi, Xlo);      // same-wave, no barrier needed
    __syncthreads();                // matrix dbuf guard
  }

  // ---- anticausal phase ----
  short8 Zhi, Zlo;
  {
    const float* zp = zin + ((size_t)ch * SROWS + tile * 64 + w * 16 + cidx) * 32 + quad * 8;
#pragma unroll
    for (int j = 0; j < 8; ++j) {
      float v = zp[j];
      unsigned short h = bf16u(v);
      Zhi[j] = (short)h;
      Zlo[j] = (short)bf16u(v - bf2f(h));
    }
  }
  stage2<DT, 32, 32, 40>(eptr<DT>(Em, (long)(s + CHS - 1) * 1024), sA[0][0], sA[0][NP - 1], tid);
  stage2<DT, 32, 16, 24>(eptr<DT>(Fm, (long)(s + CHS - 1) * 512), sB[0][0], sB[0][NP - 1], tid);
  stage1<DT, 16, 32, 40>(eptr<DT>(Gm, (long)(s + CHS - 1) * 512), sC[0], tid);
  un = ldu_raw<DT>(U, urow + (size_t)(s + CHS - 1) * 16 + qq * 8);
  __syncthreads();

  f32x4 aZ[2];
#pragma unroll 2
  for (int t = 0; t < CHS; ++t) {
    const int k = s + CHS - 1 - t, buf = t & 1;
    if (t < CHS - 1) {
      stage2<DT, 32, 32, 40>(eptr<DT>(Em, (long)(k - 1) * 1024), sA[buf ^ 1][0], sA[buf ^ 1][NP - 1], tid);
      stage2<DT, 32, 16, 24>(eptr<DT>(Fm, (long)(k - 1) * 512), sB[buf ^ 1][0], sB[buf ^ 1][NP - 1], tid);
      stage1<DT, 16, 32, 40>(eptr<DT>(Gm, (long)(k - 1) * 512), sC[buf ^ 1], tid);
    }
    short8 uh, ul;
    u_cvt<DT>(un, uh, ul);
    if (t < CHS - 1) un = ldu_raw<DT>(U, urow + (size_t)(k - 1) * 16 + qq * 8);
    const f32x4 z4 = {0.f, 0.f, 0.f, 0.f};
    const short8 gf = ldfrag32(sC[buf], lane, 0);
    f32x4 ya = MFMA16(Zhi, gf, z4);
    ya = MFMA16(Zlo, gf, ya);
    {  // RMW: add anticausal contribution to stored causal partial (same thread wrote it)
      const size_t obase = (size_t)(tile * 64 + w * 16 + quad * 4) * 8192 + (size_t)k * 16 + cidx;
      if constexpr (DT == 0) {
        short* o = (short*)out;
#pragma unroll
        for (int r = 0; r < 4; ++r) {
          const float c = bf2f((unsigned short)o[obase + (size_t)r * 8192]);
          o[obase + (size_t)r * 8192] = (short)bf16u(c + ya[r]);
        }
      } else {
        float* o = (float*)out;
#pragma unroll
        for (int r = 0; r < 4; ++r) o[obase + (size_t)r * 8192] += ya[r];
      }
    }
    step_state<DT>(Zhi, Zlo, uh, ul, sA[buf][0], sA[buf][NP - 1], sB[buf][0], sB[buf][NP - 1], aZ, lane);
    twr(aZ, T[w], lane);
    trd(T[w], lane, Zhi, Zlo);
    __syncthreads();
  }
}

extern "C" void kernel_launch(void* const* d_in, const int* in_sizes, int n_in,
                              void* d_out, int out_size, void* d_ws, size_t ws_size,
                              hipStream_t stream) {
  (void)in_sizes; (void)n_in; (void)out_size; (void)ws_size;
  const void* U = d_in[0];
  const void* A = d_in[1];
  const void* B = d_in[2];
  const void* C = d_in[3];
  const void* D = d_in[4];
  const void* E = d_in[5];
  const void* F = d_in[6];
  const void* G = d_in[7];
  const void* bias = d_in[8];

  int* flag = (int*)d_ws;
  float* Sc = (float*)((char*)d_ws + 1024);
  float* Sa = Sc + (size_t)NCH * SROWS * 32;

  k_detect<<<1, 64, 0, stream>>>((const unsigned short*)U, flag);
  k1_scan<0><<<dim3(NCH, 65), 256, 0, stream>>>(flag, U, A, B, E, F, Sc, Sa);
  k1_scan<1><<<dim3(NCH, 65), 256, 0, stream>>>(flag, U, A, B, E, F, Sc, Sa);
  k2_comb<<<dim3(BATCH / 8, 2), 256, 0, stream>>>(Sc, Sa);
  k3_scan<0><<<dim3(NCH, 64), 256, 0, stream>>>(flag, U, A, B, C, D, E, F, G, bias, Sc, Sa, d_out);
  k3_scan<1><<<dim3(NCH, 64), 256, 0, stream>>>(flag, U, A, B, C, D, E, F, G, bias, Sc, Sa, d_out);
}

// Round 4
// 609.492 us; speedup vs baseline: 2.3166x; 1.4738x over previous
//
#include <hip/hip_runtime.h>

// SemiseparableLayer on MI355X (gfx950) — v5: v4 (verified, 898us) + one-time k_prep.
// Discovery from v4 counters: live inputs are FP32 (LDS_Block_Size=51200 = DT=1 variant).
// The per-stage fp32->bf16 hi/lo converting stagers and u_cvt dominate the serial loop.
// v5 moves ALL matrix conversion to a one-time k_prep writing ws blobs whose layout is
// byte-identical to the (verified) v4 LDS layout; in-loop staging becomes raw
// global_load_lds 1KB chunks. Optionally (ws permitting) U is pre-converted too.
// Scan-loop compute (step_state/twr/trd/ldfrag/barriers/outputs) is v4 VERBATIM ->
// bit-identical numerics. Host picks mode by ws_size:
//   mode 2: blobs + Ub (needs ~154.2 MB)   mode 1: blobs (needs ~26.2 MB)
//   mode 0: v4 behavior exactly (16.9 MB)

#define BATCH 4096
#define NCH   16
#define CHS   32
#define SROWS (BATCH + 32)
#define TSTR  36

typedef __attribute__((ext_vector_type(8))) short short8;
typedef __attribute__((ext_vector_type(4))) float f32x4;
typedef short8 __attribute__((may_alias)) short8a;
typedef f32x4 __attribute__((may_alias)) f32x4a;
typedef unsigned __attribute__((may_alias)) uinta;

#define MFMA16(a, b, c) __builtin_amdgcn_mfma_f32_16x16x32_bf16(a, b, c, 0, 0, 0)

__device__ __forceinline__ unsigned short bf16u(float x) {
  unsigned u = __builtin_bit_cast(unsigned, x);
  u += 0x7fffu + ((u >> 16) & 1u);
  return (unsigned short)(u >> 16);
}
__device__ __forceinline__ float bf2f(unsigned short u) {
  return __builtin_bit_cast(float, ((unsigned)u) << 16);
}
template <int DT>
__device__ __forceinline__ const void* eptr(const void* b, long e) {
  return (const char*)b + e * (DT ? 4 : 2);
}

// ---------------- async global->LDS (raw blob staging, guide-verified m97 pattern) ----
__device__ __forceinline__ void gload16(const void* g, void* lds) {
  __builtin_amdgcn_global_load_lds((const __attribute__((address_space(1))) void*)g,
                                   (__attribute__((address_space(3))) void*)lds, 16, 0, 0);
}
// 8 KB blob: wave w copies chunks 2w, 2w+1 (1 KB each; dest wave-uniform + lane*16)
__device__ __forceinline__ void stage_blob8(const short* g, short* lds, int w, int lane) {
#pragma unroll
  for (int c = 0; c < 2; ++c) {
    const int ob = (w * 2 + c) * 1024;
    gload16((const char*)g + ob + lane * 16, (char*)lds + ob);
  }
}
// 2 KB blob: waves 0,1 copy 1 KB each
__device__ __forceinline__ void stage_blob2k(const short* g, short* lds, int w, int lane) {
  if (w < 2) {
    const int ob = w * 1024;
    gload16((const char*)g + ob + lane * 16, (char*)lds + ob);
  }
}

// ---------------- converting stagers (mode 0; v4 verbatim, verified) ----------------
template <int DT, int ROWS, int COLS, int PSTR>
__device__ __forceinline__ void stage2(const void* gp, short* hi, short* lo, int tid) {
  if constexpr (DT == 0) {
    const uinta* gu = (const uinta*)gp;
    for (int i = tid; i < ROWS * COLS / 2; i += 256) {
      int r = i / (COLS / 2), c = i - r * (COLS / 2);
      ((uinta*)(hi + r * PSTR))[c] = gu[i];
    }
  } else {
    const float* gf = (const float*)gp;
    for (int i = tid; i < ROWS * COLS; i += 256) {
      int r = i / COLS, c = i - r * COLS;
      float v = gf[i];
      unsigned short h = bf16u(v);
      hi[r * PSTR + c] = (short)h;
      lo[r * PSTR + c] = (short)bf16u(v - bf2f(h));
    }
  }
}
template <int DT, int ROWS, int COLS, int PSTR>
__device__ __forceinline__ void stage1(const void* gp, short* hi, int tid) {
  if constexpr (DT == 0) {
    const uinta* gu = (const uinta*)gp;
    for (int i = tid; i < ROWS * COLS / 2; i += 256) {
      int r = i / (COLS / 2), c = i - r * (COLS / 2);
      ((uinta*)(hi + r * PSTR))[c] = gu[i];
    }
  } else {
    const float* gf = (const float*)gp;
    for (int i = tid; i < ROWS * COLS; i += 256) {
      int r = i / COLS, c = i - r * COLS;
      hi[r * PSTR + c] = (short)bf16u(gf[i]);
    }
  }
}

// ---------------- fragment loaders (v4 verbatim) ----------------
__device__ __forceinline__ short8 ldfrag32(const short* l, int lane, int nbase) {
  int n = nbase + (lane & 15), q = lane >> 4;
  return *(const short8a*)(l + n * 40 + q * 8);
}
__device__ __forceinline__ short8 ldfrag16(const short* l, int lane, int nbase) {
  int n = nbase + (lane & 15), q = lane >> 4;
  short8 z = {};
  if (q < 2) z = *(const short8a*)(l + n * 24 + q * 8);
  return z;
}

// fp32 C-layout -> fp32 plane; plane -> A-frag w/ reader-side hi/lo split (v4 verbatim)
__device__ __forceinline__ void twr(const f32x4* acc, float* T, int lane) {
  const int c = lane & 15, q = lane >> 4;
#pragma unroll
  for (int h = 0; h < 2; ++h)
#pragma unroll
    for (int r = 0; r < 4; ++r) T[(q * 4 + r) * TSTR + h * 16 + c] = acc[h][r];
}
__device__ __forceinline__ void trd(const float* T, int lane, short8& hi, short8& lo) {
  const int m = lane & 15, q = lane >> 4;
  const float* p = T + m * TSTR + q * 8;
#pragma unroll
  for (int j = 0; j < 8; ++j) {
    float v = p[j];
    unsigned short h = bf16u(v);
    hi[j] = (short)h;
    lo[j] = (short)bf16u(v - bf2f(h));
  }
}

// ---------------- u loaders (v4 verbatim + mode-2 preconverted path) ----------------
template <int DT> struct URaw;
template <> struct URaw<0> { short8 s; };
template <> struct URaw<1> { f32x4 a, b; };

template <int DT>
__device__ __forceinline__ URaw<DT> ldu_raw(const void* U, size_t off) {
  URaw<DT> r;
  if constexpr (DT == 0) {
    r.s = *(const short8a*)((const short*)U + off);
  } else {
    const f32x4a* p = (const f32x4a*)((const float*)U + off);
    r.a = p[0];
    r.b = p[1];
  }
  return r;
}
template <int DT>
__device__ __forceinline__ void u_cvt(const URaw<DT>& r, short8& uhi, short8& ulo) {
  if constexpr (DT == 0) {
    uhi = r.s;
    ulo = short8{};
  } else {
#pragma unroll
    for (int j = 0; j < 4; ++j) {
      float v = r.a[j];
      unsigned short h = bf16u(v);
      uhi[j] = (short)h;
      ulo[j] = (short)bf16u(v - bf2f(h));
    }
#pragma unroll
    for (int j = 0; j < 4; ++j) {
      float v = r.b[j];
      unsigned short h = bf16u(v);
      uhi[4 + j] = (short)h;
      ulo[4 + j] = (short)bf16u(v - bf2f(h));
    }
  }
}
// mode dispatcher: fetch() issues raw loads (prefetchable), get() converts/unpacks
template <int DT, int MODE> struct UL {
  URaw<DT> r;
  __device__ __forceinline__ void fetch(const void* U, const short*, size_t row, int k, int qq) {
    r = ldu_raw<DT>(U, row * 8192 + (size_t)k * 16 + qq * 8);
  }
  __device__ __forceinline__ void get(short8& hi, short8& lo) const { u_cvt<DT>(r, hi, lo); }
};
template <> struct UL<1, 2> {  // preconverted Ub: [row][k*2+qq]{hi8,lo8}
  short8 h, l;
  __device__ __forceinline__ void fetch(const void*, const short* Ub, size_t row, int k, int qq) {
    const short* p = Ub + (row * 1024 + (size_t)k * 2 + qq) * 16;
    h = *(const short8a*)p;
    l = *(const short8a*)(p + 8);
  }
  __device__ __forceinline__ void get(short8& hi, short8& lo) const { hi = h; lo = l; }
};

template <int DT>
__device__ __forceinline__ float ldbias(const void* b, int i) {
  if constexpr (DT == 0) return bf2f((unsigned short)((const short*)b)[i]);
  else return ((const float*)b)[i];
}

// one state update (v4 verbatim)
template <int DT>
__device__ __forceinline__ void step_state(const short8& Xhi, const short8& Xlo,
                                           const short8& uhi, const short8& ulo,
                                           const short* Mhi, const short* Mlo,
                                           const short* Bhi, const short* Blo,
                                           f32x4* out, int lane) {
#pragma unroll
  for (int h = 0; h < 2; ++h) {
    const f32x4 z4 = {0.f, 0.f, 0.f, 0.f};
    short8 bA = ldfrag32(Mhi, lane, h * 16);
    f32x4 ax = MFMA16(Xhi, bA, z4);
    ax = MFMA16(Xlo, bA, ax);
    short8 bB = ldfrag16(Bhi, lane, h * 16);
    ax = MFMA16(uhi, bB, ax);
    if constexpr (DT) {
      short8 bAl = ldfrag32(Mlo, lane, h * 16);
      ax = MFMA16(Xhi, bAl, ax);
      ax = MFMA16(ulo, bB, ax);
      short8 bBl = ldfrag16(Blo, lane, h * 16);
      ax = MFMA16(uhi, bBl, ax);
    }
    out[h] = ax;
  }
}

// ---------------- dtype detector (wave-parallel) ----------------
__global__ void k_detect(const unsigned short* __restrict__ U16, int* __restrict__ flag) {
  int lane = threadIdx.x;
  int bad = 0;
  for (int i = lane; i < 512; i += 64) {
    int e = (U16[i] >> 7) & 0xFF;
    bad += ((e > 134) || (e < 96 && e != 0)) ? 1 : 0;
  }
#pragma unroll
  for (int s = 32; s; s >>= 1) bad += __shfl_xor(bad, s);
  if (lane == 0) *flag = (bad > 48) ? 1 : 0;
}

// ---------------- k_prep: one-time matrix -> bf16 hi/lo blobs (LDS-layout-exact) ------
// ABb[k] (8KB): Ahi[32][40] | Alo | Bhi[32][24] | Blo   EFb[k]: same for E,F
// CDb[k] (2KB): Chi[16][40] | Dhi[16][24]               Gb[k]:  Ghi[16][40] | pad
template <int DT, int ROWS, int COLS, int PSTR, bool LO>
__device__ __forceinline__ void cvt_mat(const void* gp, short* hi, short* lo, int tid) {
  if constexpr (DT == 0) {
    const unsigned short* gs = (const unsigned short*)gp;
    for (int i = tid; i < ROWS * COLS; i += 256) {
      int r = i / COLS, c = i - r * COLS;
      hi[r * PSTR + c] = (short)gs[i];
    }
  } else {
    const float* gf = (const float*)gp;
    for (int i = tid; i < ROWS * COLS; i += 256) {
      int r = i / COLS, c = i - r * COLS;
      float v = gf[i];
      unsigned short h = bf16u(v);
      hi[r * PSTR + c] = (short)h;
      if constexpr (LO) lo[r * PSTR + c] = (short)bf16u(v - bf2f(h));
    }
  }
}
template <int DT>
__global__ __launch_bounds__(256) void k_prep(
    const int* __restrict__ flagp,
    const void* __restrict__ Am, const void* __restrict__ Bm, const void* __restrict__ Cm,
    const void* __restrict__ Dm, const void* __restrict__ Em, const void* __restrict__ Fm,
    const void* __restrict__ Gm,
    short* __restrict__ ABb, short* __restrict__ EFb, short* __restrict__ CDb,
    short* __restrict__ Gb) {
  if (*flagp != DT) return;
  const int k = blockIdx.x, tid = threadIdx.x;
  short* ab = ABb + (size_t)k * 4096;
  short* ef = EFb + (size_t)k * 4096;
  short* cd = CDb + (size_t)k * 1024;
  short* gb = Gb + (size_t)k * 1024;
  cvt_mat<DT, 32, 32, 40, true>(eptr<DT>(Am, (long)k * 1024), ab, ab + 1280, tid);
  cvt_mat<DT, 32, 16, 24, true>(eptr<DT>(Bm, (long)k * 512), ab + 2560, ab + 3328, tid);
  cvt_mat<DT, 32, 32, 40, true>(eptr<DT>(Em, (long)k * 1024), ef, ef + 1280, tid);
  cvt_mat<DT, 32, 16, 24, true>(eptr<DT>(Fm, (long)k * 512), ef + 2560, ef + 3328, tid);
  cvt_mat<DT, 16, 32, 40, false>(eptr<DT>(Cm, (long)k * 512), cd, nullptr, tid);
  cvt_mat<DT, 16, 16, 24, false>(eptr<DT>(Dm, (long)k * 256), cd + 640, nullptr, tid);
  cvt_mat<DT, 16, 32, 40, false>(eptr<DT>(Gm, (long)k * 512), gb, nullptr, tid);
}
// mode-2 only: U fp32 -> interleaved hi/lo bf16 pairs (same scalar cvt as u_cvt<1>)
__global__ __launch_bounds__(256) void k_prepU(const int* __restrict__ flagp,
                                               const float* __restrict__ Uf,
                                               short* __restrict__ Ub) {
  if (*flagp != 1) return;
  const size_t i = (size_t)blockIdx.x * 256 + threadIdx.x;
  const f32x4a* p = (const f32x4a*)(Uf + i * 8);
  f32x4 a = p[0], b = p[1];
  short8 hi, lo;
#pragma unroll
  for (int j = 0; j < 4; ++j) {
    unsigned short h = bf16u(a[j]);
    hi[j] = (short)h;
    lo[j] = (short)bf16u(a[j] - bf2f(h));
  }
#pragma unroll
  for (int j = 0; j < 4; ++j) {
    unsigned short h = bf16u(b[j]);
    hi[4 + j] = (short)h;
    lo[4 + j] = (short)bf16u(b[j] - bf2f(h));
  }
  *(short8a*)(Ub + i * 16) = hi;
  *(short8a*)(Ub + i * 16 + 8) = lo;
}

// ---------------- K1: chunk-local scans from zero (+ identity tile -> P^T) ----------
template <int DT, int MODE>
__global__ __launch_bounds__(256, 4) void k1_scan(
    const int* __restrict__ flagp, const void* __restrict__ U,
    const void* __restrict__ Am, const void* __restrict__ Bm,
    const void* __restrict__ Em, const void* __restrict__ Fm,
    const short* __restrict__ ABb, const short* __restrict__ EFb,
    const short* __restrict__ Ub,
    float* __restrict__ Sc, float* __restrict__ Sa) {
  if (*flagp != DT) return;
  const int ch = blockIdx.x, tile = blockIdx.y;
  const bool ident = (tile == 64);
  const int tid = threadIdx.x, lane = tid & 63, w = tid >> 6;
  const int s = ch * CHS;
  __shared__ __align__(16) short bAB[2][4096];
  __shared__ __align__(16) short bEF[2][4096];
  __shared__ __align__(16) float T[4][2][16 * TSTR];

  short8 Xhi = {}, Xlo = {}, Zhi = {}, Zlo = {};
  if (ident) {
    const int m = lane & 15, q = lane >> 4;
    short8 id = {};
#pragma unroll
    for (int j = 0; j < 8; ++j) id[j] = ((q * 8 + j) == (w * 16 + m)) ? (short)0x3F80 : (short)0;
    Xhi = id; Zhi = id;
  }

  auto stAB = [&](int k, int b) {
    if constexpr (MODE >= 1) {
      stage_blob8(ABb + (size_t)k * 4096, bAB[b], w, lane);
    } else {
      stage2<DT, 32, 32, 40>(eptr<DT>(Am, (long)k * 1024), bAB[b], bAB[b] + 1280, tid);
      stage2<DT, 32, 16, 24>(eptr<DT>(Bm, (long)k * 512), bAB[b] + 2560, bAB[b] + 3328, tid);
    }
  };
  auto stEF = [&](int k, int b) {
    if constexpr (MODE >= 1) {
      stage_blob8(EFb + (size_t)k * 4096, bEF[b], w, lane);
    } else {
      stage2<DT, 32, 32, 40>(eptr<DT>(Em, (long)k * 1024), bEF[b], bEF[b] + 1280, tid);
      stage2<DT, 32, 16, 24>(eptr<DT>(Fm, (long)k * 512), bEF[b] + 2560, bEF[b] + 3328, tid);
    }
  };

  stAB(s, 0);
  stEF(s + CHS - 1, 0);

  const size_t row = (size_t)(ident ? 0 : (tile * 64 + w * 16 + (lane & 15)));
  const int qq = (lane >> 4) & 1;
  UL<DT, MODE> upc, upa;
  if (!ident) {
    upc.fetch(U, Ub, row, s, qq);
    upa.fetch(U, Ub, row, s + CHS - 1, qq);
  }
  __syncthreads();

  f32x4 aX[2], aZ[2];
#pragma unroll 2
  for (int t = 0; t < CHS; ++t) {
    const int kc = s + t, ka = s + CHS - 1 - t, buf = t & 1;
    if (t < CHS - 1) {
      stAB(kc + 1, buf ^ 1);
      stEF(ka - 1, buf ^ 1);
    }
    short8 uch = {}, ucl = {}, uah = {}, ual = {};
    if (!ident) {
      upc.get(uch, ucl);
      upa.get(uah, ual);
      if (t < CHS - 1) {
        upc.fetch(U, Ub, row, kc + 1, qq);
        upa.fetch(U, Ub, row, ka - 1, qq);
      }
    }
    step_state<DT>(Xhi, Xlo, uch, ucl, bAB[buf], bAB[buf] + 1280, bAB[buf] + 2560,
                   bAB[buf] + 3328, aX, lane);
    step_state<DT>(Zhi, Zlo, uah, ual, bEF[buf], bEF[buf] + 1280, bEF[buf] + 2560,
                   bEF[buf] + 3328, aZ, lane);
    twr(aX, T[w][0], lane);
    twr(aZ, T[w][1], lane);
    trd(T[w][0], lane, Xhi, Xlo);   // same-wave T round trip: lgkmcnt suffices
    trd(T[w][1], lane, Zhi, Zlo);
    __syncthreads();                // guards matrix double-buffer
  }

  if (!ident || w < 2) {
    const int grow = tile * 64 + w * 16;
#pragma unroll
    for (int h = 0; h < 2; ++h)
#pragma unroll
      for (int r = 0; r < 4; ++r) {
        const int m = (lane >> 4) * 4 + r, col = h * 16 + (lane & 15);
        const size_t off = ((size_t)ch * SROWS + grow + m) * 32 + col;
        Sc[off] = aX[h][r];
        Sa[off] = aZ[h][r];
      }
  }
}

// ---------------- K2: sequential fp32 combine over chunks (v1 verbatim) ----------------
__global__ __launch_bounds__(256) void k2_comb(float* __restrict__ Sc, float* __restrict__ Sa) {
  const int dir = blockIdx.y;
  const int r = threadIdx.x >> 5, j = threadIdx.x & 31;
  const int row = blockIdx.x * 8 + r;
  float* S = dir ? Sa : Sc;
  __shared__ float P[32][33];
  __shared__ float xs[8][33];
  float x = 0.f;
  for (int it = 0; it < NCH; ++it) {
    const int ch = dir ? (NCH - 1 - it) : it;
    const size_t base = ((size_t)ch * SROWS + row) * 32 + j;
    const float s_local = S[base];
    for (int i = threadIdx.x; i < 1024; i += 256)
      P[i >> 5][i & 31] = S[((size_t)ch * SROWS + BATCH + (i >> 5)) * 32 + (i & 31)];
    xs[r][j] = x;
    __syncthreads();
    S[base] = x;
    float acc = s_local;
#pragma unroll
    for (int m = 0; m < 32; ++m) acc += xs[r][m] * P[m][j];
    x = acc;
    __syncthreads();
  }
}

// ---------------- K3: re-scan with true entry states, produce y ----------------
template <int DT, int MODE>
__global__ __launch_bounds__(256, 4) void k3_scan(
    const int* __restrict__ flagp, const void* __restrict__ U,
    const void* __restrict__ Am, const void* __restrict__ Bm,
    const void* __restrict__ Cm, const void* __restrict__ Dm,
    const void* __restrict__ Em, const void* __restrict__ Fm,
    const void* __restrict__ Gm, const void* __restrict__ biasv,
    const short* __restrict__ ABb, const short* __restrict__ EFb,
    const short* __restrict__ CDb, const short* __restrict__ Gb,
    const short* __restrict__ Ub,
    const float* __restrict__ xin, const float* __restrict__ zin,
    void* __restrict__ out) {
  if (*flagp != DT) return;
  const int ch = blockIdx.x, tile = blockIdx.y;
  const int tid = threadIdx.x, lane = tid & 63, w = tid >> 6;
  const int s = ch * CHS;
  __shared__ __align__(16) short bM[2][4096];
  __shared__ __align__(16) short bO[2][1024];
  __shared__ __align__(16) float T[4][16 * TSTR];
  const int cidx = lane & 15, quad = lane >> 4, qq = quad & 1;
  const size_t row = (size_t)(tile * 64 + w * 16 + cidx);

  auto stC = [&](int k, int b) {
    if constexpr (MODE >= 1) {
      stage_blob8(ABb + (size_t)k * 4096, bM[b], w, lane);
      stage_blob2k(CDb + (size_t)k * 1024, bO[b], w, lane);
    } else {
      stage2<DT, 32, 32, 40>(eptr<DT>(Am, (long)k * 1024), bM[b], bM[b] + 1280, tid);
      stage2<DT, 32, 16, 24>(eptr<DT>(Bm, (long)k * 512), bM[b] + 2560, bM[b] + 3328, tid);
      stage1<DT, 16, 32, 40>(eptr<DT>(Cm, (long)k * 512), bO[b], tid);
      stage1<DT, 16, 16, 24>(eptr<DT>(Dm, (long)k * 256), bO[b] + 640, tid);
    }
  };
  auto stA = [&](int k, int b) {
    if constexpr (MODE >= 1) {
      stage_blob8(EFb + (size_t)k * 4096, bM[b], w, lane);
      stage_blob2k(Gb + (size_t)k * 1024, bO[b], w, lane);
    } else {
      stage2<DT, 32, 32, 40>(eptr<DT>(Em, (long)k * 1024), bM[b], bM[b] + 1280, tid);
      stage2<DT, 32, 16, 24>(eptr<DT>(Fm, (long)k * 512), bM[b] + 2560, bM[b] + 3328, tid);
      stage1<DT, 16, 32, 40>(eptr<DT>(Gm, (long)k * 512), bO[b], tid);
    }
  };

  // ---- causal phase ----
  short8 Xhi, Xlo;
  {
    const float* xp = xin + ((size_t)ch * SROWS + row) * 32 + quad * 8;
#pragma unroll
    for (int j = 0; j < 8; ++j) {
      float v = xp[j];
      unsigned short h = bf16u(v);
      Xhi[j] = (short)h;
      Xlo[j] = (short)bf16u(v - bf2f(h));
    }
  }
  stC(s, 0);
  UL<DT, MODE> up;
  up.fetch(U, Ub, row, s, qq);
  __syncthreads();

  f32x4 aX[2];
#pragma unroll 2
  for (int t = 0; t < CHS; ++t) {
    const int k = s + t, buf = t & 1;
    if (t < CHS - 1) stC(k + 1, buf ^ 1);
    short8 uh, ul;
    up.get(uh, ul);
    if (t < CHS - 1) up.fetch(U, Ub, row, k + 1, qq);
    const f32x4 z4 = {0.f, 0.f, 0.f, 0.f};
    const short8 cf = ldfrag32(bO[buf], lane, 0);
    f32x4 ya = MFMA16(Xhi, cf, z4);
    ya = MFMA16(Xlo, cf, ya);
    const short8 df = ldfrag16(bO[buf] + 640, lane, 0);
    ya = MFMA16(uh, df, ya);
    if constexpr (DT) ya = MFMA16(ul, df, ya);
    const float bv = ldbias<DT>(biasv, k * 16 + cidx);
    {
      const size_t obase = (size_t)(tile * 64 + w * 16 + quad * 4) * 8192 + (size_t)k * 16 + cidx;
      if constexpr (DT == 0) {
        short* o = (short*)out;
#pragma unroll
        for (int r = 0; r < 4; ++r) o[obase + (size_t)r * 8192] = (short)bf16u(ya[r] + bv);
      } else {
        float* o = (float*)out;
#pragma unroll
        for (int r = 0; r < 4; ++r) o[obase + (size_t)r * 8192] = ya[r] + bv;
      }
    }
    step_state<DT>(Xhi, Xlo, uh, ul, bM[buf], bM[buf] + 1280, bM[buf] + 2560, bM[buf] + 3328,
                   aX, lane);
    twr(aX, T[w], lane);
    trd(T[w], lane, Xhi, Xlo);
    __syncthreads();
  }

  // ---- anticausal phase ----
  short8 Zhi, Zlo;
  {
    const float* zp = zin + ((size_t)ch * SROWS + row) * 32 + quad * 8;
#pragma unroll
    for (int j = 0; j < 8; ++j) {
      float v = zp[j];
      unsigned short h = bf16u(v);
      Zhi[j] = (short)h;
      Zlo[j] = (short)bf16u(v - bf2f(h));
    }
  }
  stA(s + CHS - 1, 0);
  up.fetch(U, Ub, row, s + CHS - 1, qq);
  __syncthreads();

  f32x4 aZ[2];
#pragma unroll 2
  for (int t = 0; t < CHS; ++t) {
    const int k = s + CHS - 1 - t, buf = t & 1;
    if (t < CHS - 1) stA(k - 1, buf ^ 1);
    short8 uh, ul;
    up.get(uh, ul);
    if (t < CHS - 1) up.fetch(U, Ub, row, k - 1, qq);
    const f32x4 z4 = {0.f, 0.f, 0.f, 0.f};
    const short8 gf = ldfrag32(bO[buf], lane, 0);
    f32x4 ya = MFMA16(Zhi, gf, z4);
    ya = MFMA16(Zlo, gf, ya);
    {
      const size_t obase = (size_t)(tile * 64 + w * 16 + quad * 4) * 8192 + (size_t)k * 16 + cidx;
      if constexpr (DT == 0) {
        short* o = (short*)out;
#pragma unroll
        for (int r = 0; r < 4; ++r) {
          const float c = bf2f((unsigned short)o[obase + (size_t)r * 8192]);
          o[obase + (size_t)r * 8192] = (short)bf16u(c + ya[r]);
        }
      } else {
        float* o = (float*)out;
#pragma unroll
        for (int r = 0; r < 4; ++r) o[obase + (size_t)r * 8192] += ya[r];
      }
    }
    step_state<DT>(Zhi, Zlo, uh, ul, bM[buf], bM[buf] + 1280, bM[buf] + 2560, bM[buf] + 3328,
                   aZ, lane);
    twr(aZ, T[w], lane);
    trd(T[w], lane, Zhi, Zlo);
    __syncthreads();
  }
}

extern "C" void kernel_launch(void* const* d_in, const int* in_sizes, int n_in,
                              void* d_out, int out_size, void* d_ws, size_t ws_size,
                              hipStream_t stream) {
  (void)in_sizes; (void)n_in; (void)out_size;
  const void* U = d_in[0];
  const void* A = d_in[1];
  const void* B = d_in[2];
  const void* C = d_in[3];
  const void* D = d_in[4];
  const void* E = d_in[5];
  const void* F = d_in[6];
  const void* G = d_in[7];
  const void* bias = d_in[8];

  constexpr size_t SC1 = (size_t)NCH * SROWS * 32;           // floats per S buffer
  constexpr size_t BLOBS = (size_t)512 * 8192 * 2 + (size_t)512 * 2048 * 2;  // 10,485,760 B
  constexpr size_t UBB = (size_t)BATCH * 1024 * 32;          // 134,217,728 B
  constexpr size_t NEED1 = 1024 + BLOBS + SC1 * 8;           // 27,395,072 B
  constexpr size_t NEED2 = NEED1 + UBB;                      // 161,612,800 B
  const int mode = (ws_size >= NEED2) ? 2 : (ws_size >= NEED1 ? 1 : 0);

  char* base = (char*)d_ws;
  int* flag = (int*)base;
  short* ABb = (short*)(base + 1024);
  short* EFb = ABb + (size_t)512 * 4096;
  short* CDb = EFb + (size_t)512 * 4096;
  short* Gb = CDb + (size_t)512 * 1024;
  float* Sc = (mode >= 1) ? (float*)(Gb + (size_t)512 * 1024) : (float*)(base + 1024);
  float* Sa = Sc + SC1;
  short* Ub = (short*)(Sa + SC1);

  k_detect<<<1, 64, 0, stream>>>((const unsigned short*)U, flag);
  if (mode >= 1) {
    k_prep<0><<<512, 256, 0, stream>>>(flag, A, B, C, D, E, F, G, ABb, EFb, CDb, Gb);
    k_prep<1><<<512, 256, 0, stream>>>(flag, A, B, C, D, E, F, G, ABb, EFb, CDb, Gb);
  }
  if (mode == 2) k_prepU<<<16384, 256, 0, stream>>>(flag, (const float*)U, Ub);

  if (mode == 2) {
    k1_scan<0, 1><<<dim3(NCH, 65), 256, 0, stream>>>(flag, U, A, B, E, F, ABb, EFb, Ub, Sc, Sa);
    k1_scan<1, 2><<<dim3(NCH, 65), 256, 0, stream>>>(flag, U, A, B, E, F, ABb, EFb, Ub, Sc, Sa);
    k2_comb<<<dim3(BATCH / 8, 2), 256, 0, stream>>>(Sc, Sa);
    k3_scan<0, 1><<<dim3(NCH, 64), 256, 0, stream>>>(flag, U, A, B, C, D, E, F, G, bias, ABb, EFb,
                                                     CDb, Gb, Ub, Sc, Sa, d_out);
    k3_scan<1, 2><<<dim3(NCH, 64), 256, 0, stream>>>(flag, U, A, B, C, D, E, F, G, bias, ABb, EFb,
                                                     CDb, Gb, Ub, Sc, Sa, d_out);
  } else if (mode == 1) {
    k1_scan<0, 1><<<dim3(NCH, 65), 256, 0, stream>>>(flag, U, A, B, E, F, ABb, EFb, Ub, Sc, Sa);
    k1_scan<1, 1><<<dim3(NCH, 65), 256, 0, stream>>>(flag, U, A, B, E, F, ABb, EFb, Ub, Sc, Sa);
    k2_comb<<<dim3(BATCH / 8, 2), 256, 0, stream>>>(Sc, Sa);
    k3_scan<0, 1><<<dim3(NCH, 64), 256, 0, stream>>>(flag, U, A, B, C, D, E, F, G, bias, ABb, EFb,
                                                     CDb, Gb, Ub, Sc, Sa, d_out);
    k3_scan<1, 1><<<dim3(NCH, 64), 256, 0, stream>>>(flag, U, A, B, C, D, E, F, G, bias, ABb, EFb,
                                                     CDb, Gb, Ub, Sc, Sa, d_out);
  } else {
    k1_scan<0, 0><<<dim3(NCH, 65), 256, 0, stream>>>(flag, U, A, B, E, F, ABb, EFb, Ub, Sc, Sa);
    k1_scan<1, 0><<<dim3(NCH, 65), 256, 0, stream>>>(flag, U, A, B, E, F, ABb, EFb, Ub, Sc, Sa);
    k2_comb<<<dim3(BATCH / 8, 2), 256, 0, stream>>>(Sc, Sa);
    k3_scan<0, 0><<<dim3(NCH, 64), 256, 0, stream>>>(flag, U, A, B, C, D, E, F, G, bias, ABb, EFb,
                                                     CDb, Gb, Ub, Sc, Sa, d_out);
    k3_scan<1, 0><<<dim3(NCH, 64), 256, 0, stream>>>(flag, U, A, B, C, D, E, F, G, bias, ABb, EFb,
                                                     CDb, Gb, Ub, Sc, Sa, d_out);
  }
}

// Round 5
// 605.388 us; speedup vs baseline: 2.3323x; 1.0068x over previous
//
#include <hip/hip_runtime.h>

// SemiseparableLayer on MI355X (gfx950) — v6: v5 (verified, 609us) + merged k3.
// v5 counters: k3 = 198us, 602 MB HBM (U/Ub read twice + out written twice + RMW reread).
// v6 merges k3's causal+anticausal phases into ONE dual-chain loop (k1's structure + y):
//   * per-iteration: causal chain at stage s+t, anti chain at stage s+31-t
//   * out protocol: first-touching chain STORES a packed bf16-pair partial (v1's verified
//     ypk rounding); second-touching chain FINALIZES (unpack + add + store). Both touches
//     of an element are by the SAME THREAD -> program-ordered, race-free.
//   * single T-plane per wave (X then Z sequential) -> LDS 50176 B -> 3 blocks/CU.
// Everything else (k1, k2, k_prep, k_prepU, UL loaders, step_state, twr/trd, blobs,
// mode-by-ws_size selection) is v5 VERBATIM. Mode 0 keeps v5's two-phase k3.

#define BATCH 4096
#define NCH   16
#define CHS   32
#define SROWS (BATCH + 32)
#define TSTR  36

typedef __attribute__((ext_vector_type(8))) short short8;
typedef __attribute__((ext_vector_type(4))) float f32x4;
typedef short8 __attribute__((may_alias)) short8a;
typedef f32x4 __attribute__((may_alias)) f32x4a;
typedef unsigned __attribute__((may_alias)) uinta;

#define MFMA16(a, b, c) __builtin_amdgcn_mfma_f32_16x16x32_bf16(a, b, c, 0, 0, 0)

__device__ __forceinline__ unsigned short bf16u(float x) {
  unsigned u = __builtin_bit_cast(unsigned, x);
  u += 0x7fffu + ((u >> 16) & 1u);
  return (unsigned short)(u >> 16);
}
__device__ __forceinline__ float bf2f(unsigned short u) {
  return __builtin_bit_cast(float, ((unsigned)u) << 16);
}
__device__ __forceinline__ unsigned pk2(float a, float b) {
  return (unsigned)bf16u(a) | (((unsigned)bf16u(b)) << 16);
}
template <int DT>
__device__ __forceinline__ const void* eptr(const void* b, long e) {
  return (const char*)b + e * (DT ? 4 : 2);
}

// ---------------- async global->LDS blob staging ----------------
__device__ __forceinline__ void gload16(const void* g, void* lds) {
  __builtin_amdgcn_global_load_lds((const __attribute__((address_space(1))) void*)g,
                                   (__attribute__((address_space(3))) void*)lds, 16, 0, 0);
}
__device__ __forceinline__ void stage_blob8(const short* g, short* lds, int w, int lane) {
#pragma unroll
  for (int c = 0; c < 2; ++c) {
    const int ob = (w * 2 + c) * 1024;
    gload16((const char*)g + ob + lane * 16, (char*)lds + ob);
  }
}
__device__ __forceinline__ void stage_blob2k(const short* g, short* lds, int w, int lane) {
  if (w < 2) {
    const int ob = w * 1024;
    gload16((const char*)g + ob + lane * 16, (char*)lds + ob);
  }
}

// ---------------- converting stagers (mode 0 path; v4/v5 verbatim) ----------------
template <int DT, int ROWS, int COLS, int PSTR>
__device__ __forceinline__ void stage2(const void* gp, short* hi, short* lo, int tid) {
  if constexpr (DT == 0) {
    const uinta* gu = (const uinta*)gp;
    for (int i = tid; i < ROWS * COLS / 2; i += 256) {
      int r = i / (COLS / 2), c = i - r * (COLS / 2);
      ((uinta*)(hi + r * PSTR))[c] = gu[i];
    }
  } else {
    const float* gf = (const float*)gp;
    for (int i = tid; i < ROWS * COLS; i += 256) {
      int r = i / COLS, c = i - r * COLS;
      float v = gf[i];
      unsigned short h = bf16u(v);
      hi[r * PSTR + c] = (short)h;
      lo[r * PSTR + c] = (short)bf16u(v - bf2f(h));
    }
  }
}
template <int DT, int ROWS, int COLS, int PSTR>
__device__ __forceinline__ void stage1(const void* gp, short* hi, int tid) {
  if constexpr (DT == 0) {
    const uinta* gu = (const uinta*)gp;
    for (int i = tid; i < ROWS * COLS / 2; i += 256) {
      int r = i / (COLS / 2), c = i - r * (COLS / 2);
      ((uinta*)(hi + r * PSTR))[c] = gu[i];
    }
  } else {
    const float* gf = (const float*)gp;
    for (int i = tid; i < ROWS * COLS; i += 256) {
      int r = i / COLS, c = i - r * COLS;
      hi[r * PSTR + c] = (short)bf16u(gf[i]);
    }
  }
}

// ---------------- fragment loaders (v5 verbatim) ----------------
__device__ __forceinline__ short8 ldfrag32(const short* l, int lane, int nbase) {
  int n = nbase + (lane & 15), q = lane >> 4;
  return *(const short8a*)(l + n * 40 + q * 8);
}
__device__ __forceinline__ short8 ldfrag16(const short* l, int lane, int nbase) {
  int n = nbase + (lane & 15), q = lane >> 4;
  short8 z = {};
  if (q < 2) z = *(const short8a*)(l + n * 24 + q * 8);
  return z;
}

__device__ __forceinline__ void twr(const f32x4* acc, float* T, int lane) {
  const int c = lane & 15, q = lane >> 4;
#pragma unroll
  for (int h = 0; h < 2; ++h)
#pragma unroll
    for (int r = 0; r < 4; ++r) T[(q * 4 + r) * TSTR + h * 16 + c] = acc[h][r];
}
__device__ __forceinline__ void trd(const float* T, int lane, short8& hi, short8& lo) {
  const int m = lane & 15, q = lane >> 4;
  const float* p = T + m * TSTR + q * 8;
#pragma unroll
  for (int j = 0; j < 8; ++j) {
    float v = p[j];
    unsigned short h = bf16u(v);
    hi[j] = (short)h;
    lo[j] = (short)bf16u(v - bf2f(h));
  }
}

// ---------------- u loaders (v5 verbatim) ----------------
template <int DT> struct URaw;
template <> struct URaw<0> { short8 s; };
template <> struct URaw<1> { f32x4 a, b; };

template <int DT>
__device__ __forceinline__ URaw<DT> ldu_raw(const void* U, size_t off) {
  URaw<DT> r;
  if constexpr (DT == 0) {
    r.s = *(const short8a*)((const short*)U + off);
  } else {
    const f32x4a* p = (const f32x4a*)((const float*)U + off);
    r.a = p[0];
    r.b = p[1];
  }
  return r;
}
template <int DT>
__device__ __forceinline__ void u_cvt(const URaw<DT>& r, short8& uhi, short8& ulo) {
  if constexpr (DT == 0) {
    uhi = r.s;
    ulo = short8{};
  } else {
#pragma unroll
    for (int j = 0; j < 4; ++j) {
      float v = r.a[j];
      unsigned short h = bf16u(v);
      uhi[j] = (short)h;
      ulo[j] = (short)bf16u(v - bf2f(h));
    }
#pragma unroll
    for (int j = 0; j < 4; ++j) {
      float v = r.b[j];
      unsigned short h = bf16u(v);
      uhi[4 + j] = (short)h;
      ulo[4 + j] = (short)bf16u(v - bf2f(h));
    }
  }
}
template <int DT, int MODE> struct UL {
  URaw<DT> r;
  __device__ __forceinline__ void fetch(const void* U, const short*, size_t row, int k, int qq) {
    r = ldu_raw<DT>(U, row * 8192 + (size_t)k * 16 + qq * 8);
  }
  __device__ __forceinline__ void get(short8& hi, short8& lo) const { u_cvt<DT>(r, hi, lo); }
};
template <> struct UL<1, 2> {  // preconverted Ub: [row][k*2+qq]{hi8,lo8}
  short8 h, l;
  __device__ __forceinline__ void fetch(const void*, const short* Ub, size_t row, int k, int qq) {
    const short* p = Ub + (row * 1024 + (size_t)k * 2 + qq) * 16;
    h = *(const short8a*)p;
    l = *(const short8a*)(p + 8);
  }
  __device__ __forceinline__ void get(short8& hi, short8& lo) const { hi = h; lo = l; }
};

template <int DT>
__device__ __forceinline__ float ldbias(const void* b, int i) {
  if constexpr (DT == 0) return bf2f((unsigned short)((const short*)b)[i]);
  else return ((const float*)b)[i];
}

// one state update (v5 verbatim)
template <int DT>
__device__ __forceinline__ void step_state(const short8& Xhi, const short8& Xlo,
                                           const short8& uhi, const short8& ulo,
                                           const short* Mhi, const short* Mlo,
                                           const short* Bhi, const short* Blo,
                                           f32x4* out, int lane) {
#pragma unroll
  for (int h = 0; h < 2; ++h) {
    const f32x4 z4 = {0.f, 0.f, 0.f, 0.f};
    short8 bA = ldfrag32(Mhi, lane, h * 16);
    f32x4 ax = MFMA16(Xhi, bA, z4);
    ax = MFMA16(Xlo, bA, ax);
    short8 bB = ldfrag16(Bhi, lane, h * 16);
    ax = MFMA16(uhi, bB, ax);
    if constexpr (DT) {
      short8 bAl = ldfrag32(Mlo, lane, h * 16);
      ax = MFMA16(Xhi, bAl, ax);
      ax = MFMA16(ulo, bB, ax);
      short8 bBl = ldfrag16(Blo, lane, h * 16);
      ax = MFMA16(uhi, bBl, ax);
    }
    out[h] = ax;
  }
}

// ---------------- dtype detector (v5 verbatim) ----------------
__global__ void k_detect(const unsigned short* __restrict__ U16, int* __restrict__ flag) {
  int lane = threadIdx.x;
  int bad = 0;
  for (int i = lane; i < 512; i += 64) {
    int e = (U16[i] >> 7) & 0xFF;
    bad += ((e > 134) || (e < 96 && e != 0)) ? 1 : 0;
  }
#pragma unroll
  for (int s = 32; s; s >>= 1) bad += __shfl_xor(bad, s);
  if (lane == 0) *flag = (bad > 48) ? 1 : 0;
}

// ---------------- k_prep (v5 verbatim) ----------------
template <int DT, int ROWS, int COLS, int PSTR, bool LO>
__device__ __forceinline__ void cvt_mat(const void* gp, short* hi, short* lo, int tid) {
  if constexpr (DT == 0) {
    const unsigned short* gs = (const unsigned short*)gp;
    for (int i = tid; i < ROWS * COLS; i += 256) {
      int r = i / COLS, c = i - r * COLS;
      hi[r * PSTR + c] = (short)gs[i];
    }
  } else {
    const float* gf = (const float*)gp;
    for (int i = tid; i < ROWS * COLS; i += 256) {
      int r = i / COLS, c = i - r * COLS;
      float v = gf[i];
      unsigned short h = bf16u(v);
      hi[r * PSTR + c] = (short)h;
      if constexpr (LO) lo[r * PSTR + c] = (short)bf16u(v - bf2f(h));
    }
  }
}
template <int DT>
__global__ __launch_bounds__(256) void k_prep(
    const int* __restrict__ flagp,
    const void* __restrict__ Am, const void* __restrict__ Bm, const void* __restrict__ Cm,
    const void* __restrict__ Dm, const void* __restrict__ Em, const void* __restrict__ Fm,
    const void* __restrict__ Gm,
    short* __restrict__ ABb, short* __restrict__ EFb, short* __restrict__ CDb,
    short* __restrict__ Gb) {
  if (*flagp != DT) return;
  const int k = blockIdx.x, tid = threadIdx.x;
  short* ab = ABb + (size_t)k * 4096;
  short* ef = EFb + (size_t)k * 4096;
  short* cd = CDb + (size_t)k * 1024;
  short* gb = Gb + (size_t)k * 1024;
  cvt_mat<DT, 32, 32, 40, true>(eptr<DT>(Am, (long)k * 1024), ab, ab + 1280, tid);
  cvt_mat<DT, 32, 16, 24, true>(eptr<DT>(Bm, (long)k * 512), ab + 2560, ab + 3328, tid);
  cvt_mat<DT, 32, 32, 40, true>(eptr<DT>(Em, (long)k * 1024), ef, ef + 1280, tid);
  cvt_mat<DT, 32, 16, 24, true>(eptr<DT>(Fm, (long)k * 512), ef + 2560, ef + 3328, tid);
  cvt_mat<DT, 16, 32, 40, false>(eptr<DT>(Cm, (long)k * 512), cd, nullptr, tid);
  cvt_mat<DT, 16, 16, 24, false>(eptr<DT>(Dm, (long)k * 256), cd + 640, nullptr, tid);
  cvt_mat<DT, 16, 32, 40, false>(eptr<DT>(Gm, (long)k * 512), gb, nullptr, tid);
}
__global__ __launch_bounds__(256) void k_prepU(const int* __restrict__ flagp,
                                               const float* __restrict__ Uf,
                                               short* __restrict__ Ub) {
  if (*flagp != 1) return;
  const size_t i = (size_t)blockIdx.x * 256 + threadIdx.x;
  const f32x4a* p = (const f32x4a*)(Uf + i * 8);
  f32x4 a = p[0], b = p[1];
  short8 hi, lo;
#pragma unroll
  for (int j = 0; j < 4; ++j) {
    unsigned short h = bf16u(a[j]);
    hi[j] = (short)h;
    lo[j] = (short)bf16u(a[j] - bf2f(h));
  }
#pragma unroll
  for (int j = 0; j < 4; ++j) {
    unsigned short h = bf16u(b[j]);
    hi[4 + j] = (short)h;
    lo[4 + j] = (short)bf16u(b[j] - bf2f(h));
  }
  *(short8a*)(Ub + i * 16) = hi;
  *(short8a*)(Ub + i * 16 + 8) = lo;
}

// ---------------- K1 (v5 verbatim, passed) ----------------
template <int DT, int MODE>
__global__ __launch_bounds__(256, 4) void k1_scan(
    const int* __restrict__ flagp, const void* __restrict__ U,
    const void* __restrict__ Am, const void* __restrict__ Bm,
    const void* __restrict__ Em, const void* __restrict__ Fm,
    const short* __restrict__ ABb, const short* __restrict__ EFb,
    const short* __restrict__ Ub,
    float* __restrict__ Sc, float* __restrict__ Sa) {
  if (*flagp != DT) return;
  const int ch = blockIdx.x, tile = blockIdx.y;
  const bool ident = (tile == 64);
  const int tid = threadIdx.x, lane = tid & 63, w = tid >> 6;
  const int s = ch * CHS;
  __shared__ __align__(16) short bAB[2][4096];
  __shared__ __align__(16) short bEF[2][4096];
  __shared__ __align__(16) float T[4][2][16 * TSTR];

  short8 Xhi = {}, Xlo = {}, Zhi = {}, Zlo = {};
  if (ident) {
    const int m = lane & 15, q = lane >> 4;
    short8 id = {};
#pragma unroll
    for (int j = 0; j < 8; ++j) id[j] = ((q * 8 + j) == (w * 16 + m)) ? (short)0x3F80 : (short)0;
    Xhi = id; Zhi = id;
  }

  auto stAB = [&](int k, int b) {
    if constexpr (MODE >= 1) {
      stage_blob8(ABb + (size_t)k * 4096, bAB[b], w, lane);
    } else {
      stage2<DT, 32, 32, 40>(eptr<DT>(Am, (long)k * 1024), bAB[b], bAB[b] + 1280, tid);
      stage2<DT, 32, 16, 24>(eptr<DT>(Bm, (long)k * 512), bAB[b] + 2560, bAB[b] + 3328, tid);
    }
  };
  auto stEF = [&](int k, int b) {
    if constexpr (MODE >= 1) {
      stage_blob8(EFb + (size_t)k * 4096, bEF[b], w, lane);
    } else {
      stage2<DT, 32, 32, 40>(eptr<DT>(Em, (long)k * 1024), bEF[b], bEF[b] + 1280, tid);
      stage2<DT, 32, 16, 24>(eptr<DT>(Fm, (long)k * 512), bEF[b] + 2560, bEF[b] + 3328, tid);
    }
  };

  stAB(s, 0);
  stEF(s + CHS - 1, 0);

  const size_t row = (size_t)(ident ? 0 : (tile * 64 + w * 16 + (lane & 15)));
  const int qq = (lane >> 4) & 1;
  UL<DT, MODE> upc, upa;
  if (!ident) {
    upc.fetch(U, Ub, row, s, qq);
    upa.fetch(U, Ub, row, s + CHS - 1, qq);
  }
  __syncthreads();

  f32x4 aX[2], aZ[2];
#pragma unroll 2
  for (int t = 0; t < CHS; ++t) {
    const int kc = s + t, ka = s + CHS - 1 - t, buf = t & 1;
    if (t < CHS - 1) {
      stAB(kc + 1, buf ^ 1);
      stEF(ka - 1, buf ^ 1);
    }
    short8 uch = {}, ucl = {}, uah = {}, ual = {};
    if (!ident) {
      upc.get(uch, ucl);
      upa.get(uah, ual);
      if (t < CHS - 1) {
        upc.fetch(U, Ub, row, kc + 1, qq);
        upa.fetch(U, Ub, row, ka - 1, qq);
      }
    }
    step_state<DT>(Xhi, Xlo, uch, ucl, bAB[buf], bAB[buf] + 1280, bAB[buf] + 2560,
                   bAB[buf] + 3328, aX, lane);
    step_state<DT>(Zhi, Zlo, uah, ual, bEF[buf], bEF[buf] + 1280, bEF[buf] + 2560,
                   bEF[buf] + 3328, aZ, lane);
    twr(aX, T[w][0], lane);
    twr(aZ, T[w][1], lane);
    trd(T[w][0], lane, Xhi, Xlo);
    trd(T[w][1], lane, Zhi, Zlo);
    __syncthreads();
  }

  if (!ident || w < 2) {
    const int grow = tile * 64 + w * 16;
#pragma unroll
    for (int h = 0; h < 2; ++h)
#pragma unroll
      for (int r = 0; r < 4; ++r) {
        const int m = (lane >> 4) * 4 + r, col = h * 16 + (lane & 15);
        const size_t off = ((size_t)ch * SROWS + grow + m) * 32 + col;
        Sc[off] = aX[h][r];
        Sa[off] = aZ[h][r];
      }
  }
}

// ---------------- K2 (v1 verbatim) ----------------
__global__ __launch_bounds__(256) void k2_comb(float* __restrict__ Sc, float* __restrict__ Sa) {
  const int dir = blockIdx.y;
  const int r = threadIdx.x >> 5, j = threadIdx.x & 31;
  const int row = blockIdx.x * 8 + r;
  float* S = dir ? Sa : Sc;
  __shared__ float P[32][33];
  __shared__ float xs[8][33];
  float x = 0.f;
  for (int it = 0; it < NCH; ++it) {
    const int ch = dir ? (NCH - 1 - it) : it;
    const size_t base = ((size_t)ch * SROWS + row) * 32 + j;
    const float s_local = S[base];
    for (int i = threadIdx.x; i < 1024; i += 256)
      P[i >> 5][i & 31] = S[((size_t)ch * SROWS + BATCH + (i >> 5)) * 32 + (i & 31)];
    xs[r][j] = x;
    __syncthreads();
    S[base] = x;
    float acc = s_local;
#pragma unroll
    for (int m = 0; m < 32; ++m) acc += xs[r][m] * P[m][j];
    x = acc;
    __syncthreads();
  }
}

// ---------------- K3 merged: dual-chain single loop (mode >= 1) ----------------
template <int DT, int MODE>
__global__ __launch_bounds__(256, 3) void k3_merged(
    const int* __restrict__ flagp, const void* __restrict__ U, const void* __restrict__ biasv,
    const short* __restrict__ ABb, const short* __restrict__ EFb,
    const short* __restrict__ CDb, const short* __restrict__ Gb,
    const short* __restrict__ Ub,
    const float* __restrict__ xin, const float* __restrict__ zin,
    void* __restrict__ out) {
  if (*flagp != DT) return;
  const int ch = blockIdx.x, tile = blockIdx.y;
  const int tid = threadIdx.x, lane = tid & 63, w = tid >> 6;
  const int s = ch * CHS;
  __shared__ __align__(16) short bAB[2][4096];
  __shared__ __align__(16) short bEF[2][4096];
  __shared__ __align__(16) short bCD[2][1024];
  __shared__ __align__(16) short bG[2][1024];
  __shared__ __align__(16) float T[4][16 * TSTR];  // single plane/wave, X then Z

  const int cidx = lane & 15, quad = lane >> 4, qq = quad & 1;
  const size_t row = (size_t)(tile * 64 + w * 16 + cidx);

  // entry states
  short8 Xhi, Xlo, Zhi, Zlo;
  {
    const float* xp = xin + ((size_t)ch * SROWS + row) * 32 + quad * 8;
    const float* zp = zin + ((size_t)ch * SROWS + row) * 32 + quad * 8;
#pragma unroll
    for (int j = 0; j < 8; ++j) {
      float v = xp[j];
      unsigned short h = bf16u(v);
      Xhi[j] = (short)h;
      Xlo[j] = (short)bf16u(v - bf2f(h));
      float z = zp[j];
      unsigned short hz = bf16u(z);
      Zhi[j] = (short)hz;
      Zlo[j] = (short)bf16u(z - bf2f(hz));
    }
  }

  stage_blob8(ABb + (size_t)s * 4096, bAB[0], w, lane);
  stage_blob2k(CDb + (size_t)s * 1024, bCD[0], w, lane);
  stage_blob8(EFb + (size_t)(s + CHS - 1) * 4096, bEF[0], w, lane);
  stage_blob2k(Gb + (size_t)(s + CHS - 1) * 1024, bG[0], w, lane);
  UL<DT, MODE> upc, upa;
  upc.fetch(U, Ub, row, s, qq);
  upa.fetch(U, Ub, row, s + CHS - 1, qq);
  __syncthreads();

  f32x4 aX[2], aZ[2];
#pragma unroll 2
  for (int t = 0; t < CHS; ++t) {
    const int kc = s + t, ka = s + CHS - 1 - t, buf = t & 1;
    if (t < CHS - 1) {
      stage_blob8(ABb + (size_t)(kc + 1) * 4096, bAB[buf ^ 1], w, lane);
      stage_blob2k(CDb + (size_t)(kc + 1) * 1024, bCD[buf ^ 1], w, lane);
      stage_blob8(EFb + (size_t)(ka - 1) * 4096, bEF[buf ^ 1], w, lane);
      stage_blob2k(Gb + (size_t)(ka - 1) * 1024, bG[buf ^ 1], w, lane);
    }
    short8 uh, ul, vh, vl;
    upc.get(uh, ul);
    upa.get(vh, vl);
    if (t < CHS - 1) {
      upc.fetch(U, Ub, row, kc + 1, qq);
      upa.fetch(U, Ub, row, ka - 1, qq);
    }
    const f32x4 z4 = {0.f, 0.f, 0.f, 0.f};
    // causal y at kc
    const short8 cf = ldfrag32(bCD[buf], lane, 0);
    f32x4 yc = MFMA16(Xhi, cf, z4);
    yc = MFMA16(Xlo, cf, yc);
    const short8 df = ldfrag16(bCD[buf] + 640, lane, 0);
    yc = MFMA16(uh, df, yc);
    if constexpr (DT) yc = MFMA16(ul, df, yc);
    // anti y at ka
    const short8 gf = ldfrag32(bG[buf], lane, 0);
    f32x4 yz = MFMA16(Zhi, gf, z4);
    yz = MFMA16(Zlo, gf, yz);

    const float bv = ldbias<DT>(biasv, kc * 16 + cidx);
    const size_t rbase = (size_t)(tile * 64 + w * 16 + quad * 4) * 8192;
    const size_t oc = rbase + (size_t)kc * 16 + cidx;
    const size_t oa = rbase + (size_t)ka * 16 + cidx;
    if constexpr (DT == 0) {
      short* o = (short*)out;
      if (t < CHS / 2) {  // first touch: store partials
#pragma unroll
        for (int r = 0; r < 4; ++r) o[oc + (size_t)r * 8192] = (short)bf16u(yc[r] + bv);
#pragma unroll
        for (int r = 0; r < 4; ++r) o[oa + (size_t)r * 8192] = (short)bf16u(yz[r]);
      } else {  // second touch: finalize (same thread wrote the partial)
#pragma unroll
        for (int r = 0; r < 4; ++r) {
          const float c = bf2f((unsigned short)o[oc + (size_t)r * 8192]);
          o[oc + (size_t)r * 8192] = (short)bf16u(c + yc[r] + bv);
        }
#pragma unroll
        for (int r = 0; r < 4; ++r) {
          const float c = bf2f((unsigned short)o[oa + (size_t)r * 8192]);
          o[oa + (size_t)r * 8192] = (short)bf16u(c + yz[r]);
        }
      }
    } else {
      float* o = (float*)out;
      if (t < CHS / 2) {  // first touch: packed bf16-pair partials (v1's ypk rounding)
        *(uinta*)(o + oc) = pk2(yc[0] + bv, yc[1] + bv);
        *(uinta*)(o + oc + 2 * 8192) = pk2(yc[2] + bv, yc[3] + bv);
        *(uinta*)(o + oa) = pk2(yz[0], yz[1]);
        *(uinta*)(o + oa + 2 * 8192) = pk2(yz[2], yz[3]);
      } else {  // second touch: unpack + add + final fp32
        const unsigned p0 = *(const uinta*)(o + oc);
        const unsigned p1 = *(const uinta*)(o + oc + 2 * 8192);
        o[oc + 0 * 8192] = bf2f((unsigned short)(p0 & 0xffffu)) + yc[0] + bv;
        o[oc + 1 * 8192] = bf2f((unsigned short)(p0 >> 16)) + yc[1] + bv;
        o[oc + 2 * 8192] = bf2f((unsigned short)(p1 & 0xffffu)) + yc[2] + bv;
        o[oc + 3 * 8192] = bf2f((unsigned short)(p1 >> 16)) + yc[3] + bv;
        const unsigned q0 = *(const uinta*)(o + oa);
        const unsigned q1 = *(const uinta*)(o + oa + 2 * 8192);
        o[oa + 0 * 8192] = bf2f((unsigned short)(q0 & 0xffffu)) + yz[0];
        o[oa + 1 * 8192] = bf2f((unsigned short)(q0 >> 16)) + yz[1];
        o[oa + 2 * 8192] = bf2f((unsigned short)(q1 & 0xffffu)) + yz[2];
        o[oa + 3 * 8192] = bf2f((unsigned short)(q1 >> 16)) + yz[3];
      }
    }
    // state updates
    step_state<DT>(Xhi, Xlo, uh, ul, bAB[buf], bAB[buf] + 1280, bAB[buf] + 2560,
                   bAB[buf] + 3328, aX, lane);
    step_state<DT>(Zhi, Zlo, vh, vl, bEF[buf], bEF[buf] + 1280, bEF[buf] + 2560,
                   bEF[buf] + 3328, aZ, lane);
    twr(aX, T[w], lane);
    trd(T[w], lane, Xhi, Xlo);
    twr(aZ, T[w], lane);  // WAR on T handled by in-order DS / compiler lgkmcnt
    trd(T[w], lane, Zhi, Zlo);
    __syncthreads();
  }
}

// ---------------- K3 legacy two-phase (mode 0 fallback; v5 verbatim, MODE=0) ----------
template <int DT>
__global__ __launch_bounds__(256, 4) void k3_legacy(
    const int* __restrict__ flagp, const void* __restrict__ U,
    const void* __restrict__ Am, const void* __restrict__ Bm,
    const void* __restrict__ Cm, const void* __restrict__ Dm,
    const void* __restrict__ Em, const void* __restrict__ Fm,
    const void* __restrict__ Gm, const void* __restrict__ biasv,
    const float* __restrict__ xin, const float* __restrict__ zin,
    void* __restrict__ out) {
  if (*flagp != DT) return;
  const int ch = blockIdx.x, tile = blockIdx.y;
  const int tid = threadIdx.x, lane = tid & 63, w = tid >> 6;
  const int s = ch * CHS;
  __shared__ __align__(16) short bM[2][4096];
  __shared__ __align__(16) short bO[2][1024];
  __shared__ __align__(16) float T[4][16 * TSTR];
  const int cidx = lane & 15, quad = lane >> 4, qq = quad & 1;
  const size_t row = (size_t)(tile * 64 + w * 16 + cidx);

  auto stC = [&](int k, int b) {
    stage2<DT, 32, 32, 40>(eptr<DT>(Am, (long)k * 1024), bM[b], bM[b] + 1280, tid);
    stage2<DT, 32, 16, 24>(eptr<DT>(Bm, (long)k * 512), bM[b] + 2560, bM[b] + 3328, tid);
    stage1<DT, 16, 32, 40>(eptr<DT>(Cm, (long)k * 512), bO[b], tid);
    stage1<DT, 16, 16, 24>(eptr<DT>(Dm, (long)k * 256), bO[b] + 640, tid);
  };
  auto stA = [&](int k, int b) {
    stage2<DT, 32, 32, 40>(eptr<DT>(Em, (long)k * 1024), bM[b], bM[b] + 1280, tid);
    stage2<DT, 32, 16, 24>(eptr<DT>(Fm, (long)k * 512), bM[b] + 2560, bM[b] + 3328, tid);
    stage1<DT, 16, 32, 40>(eptr<DT>(Gm, (long)k * 512), bO[b], tid);
  };

  short8 Xhi, Xlo;
  {
    const float* xp = xin + ((size_t)ch * SROWS + row) * 32 + quad * 8;
#pragma unroll
    for (int j = 0; j < 8; ++j) {
      float v = xp[j];
      unsigned short h = bf16u(v);
      Xhi[j] = (short)h;
      Xlo[j] = (short)bf16u(v - bf2f(h));
    }
  }
  stC(s, 0);
  UL<DT, 0> up;
  up.fetch(U, nullptr, row, s, qq);
  __syncthreads();

  f32x4 aX[2];
#pragma unroll 2
  for (int t = 0; t < CHS; ++t) {
    const int k = s + t, buf = t & 1;
    if (t < CHS - 1) stC(k + 1, buf ^ 1);
    short8 uh, ul;
    up.get(uh, ul);
    if (t < CHS - 1) up.fetch(U, nullptr, row, k + 1, qq);
    const f32x4 z4 = {0.f, 0.f, 0.f, 0.f};
    const short8 cf = ldfrag32(bO[buf], lane, 0);
    f32x4 ya = MFMA16(Xhi, cf, z4);
    ya = MFMA16(Xlo, cf, ya);
    const short8 df = ldfrag16(bO[buf] + 640, lane, 0);
    ya = MFMA16(uh, df, ya);
    if constexpr (DT) ya = MFMA16(ul, df, ya);
    const float bv = ldbias<DT>(biasv, k * 16 + cidx);
    {
      const size_t obase = (size_t)(tile * 64 + w * 16 + quad * 4) * 8192 + (size_t)k * 16 + cidx;
      if constexpr (DT == 0) {
        short* o = (short*)out;
#pragma unroll
        for (int r = 0; r < 4; ++r) o[obase + (size_t)r * 8192] = (short)bf16u(ya[r] + bv);
      } else {
        float* o = (float*)out;
#pragma unroll
        for (int r = 0; r < 4; ++r) o[obase + (size_t)r * 8192] = ya[r] + bv;
      }
    }
    step_state<DT>(Xhi, Xlo, uh, ul, bM[buf], bM[buf] + 1280, bM[buf] + 2560, bM[buf] + 3328,
                   aX, lane);
    twr(aX, T[w], lane);
    trd(T[w], lane, Xhi, Xlo);
    __syncthreads();
  }

  short8 Zhi, Zlo;
  {
    const float* zp = zin + ((size_t)ch * SROWS + row) * 32 + quad * 8;
#pragma unroll
    for (int j = 0; j < 8; ++j) {
      float v = zp[j];
      unsigned short h = bf16u(v);
      Zhi[j] = (short)h;
      Zlo[j] = (short)bf16u(v - bf2f(h));
    }
  }
  stA(s + CHS - 1, 0);
  up.fetch(U, nullptr, row, s + CHS - 1, qq);
  __syncthreads();

  f32x4 aZ[2];
#pragma unroll 2
  for (int t = 0; t < CHS; ++t) {
    const int k = s + CHS - 1 - t, buf = t & 1;
    if (t < CHS - 1) stA(k - 1, buf ^ 1);
    short8 uh, ul;
    up.get(uh, ul);
    if (t < CHS - 1) up.fetch(U, nullptr, row, k - 1, qq);
    const f32x4 z4 = {0.f, 0.f, 0.f, 0.f};
    const short8 gf = ldfrag32(bO[buf], lane, 0);
    f32x4 ya = MFMA16(Zhi, gf, z4);
    ya = MFMA16(Zlo, gf, ya);
    {
      const size_t obase = (size_t)(tile * 64 + w * 16 + quad * 4) * 8192 + (size_t)k * 16 + cidx;
      if constexpr (DT == 0) {
        short* o = (short*)out;
#pragma unroll
        for (int r = 0; r < 4; ++r) {
          const float c = bf2f((unsigned short)o[obase + (size_t)r * 8192]);
          o[obase + (size_t)r * 8192] = (short)bf16u(c + ya[r]);
        }
      } else {
        float* o = (float*)out;
#pragma unroll
        for (int r = 0; r < 4; ++r) o[obase + (size_t)r * 8192] += ya[r];
      }
    }
    step_state<DT>(Zhi, Zlo, uh, ul, bM[buf], bM[buf] + 1280, bM[buf] + 2560, bM[buf] + 3328,
                   aZ, lane);
    twr(aZ, T[w], lane);
    trd(T[w], lane, Zhi, Zlo);
    __syncthreads();
  }
}

extern "C" void kernel_launch(void* const* d_in, const int* in_sizes, int n_in,
                              void* d_out, int out_size, void* d_ws, size_t ws_size,
                              hipStream_t stream) {
  (void)in_sizes; (void)n_in; (void)out_size;
  const void* U = d_in[0];
  const void* A = d_in[1];
  const void* B = d_in[2];
  const void* C = d_in[3];
  const void* D = d_in[4];
  const void* E = d_in[5];
  const void* F = d_in[6];
  const void* G = d_in[7];
  const void* bias = d_in[8];

  constexpr size_t SC1 = (size_t)NCH * SROWS * 32;
  constexpr size_t BLOBS = (size_t)512 * 8192 * 2 + (size_t)512 * 2048 * 2;
  constexpr size_t UBB = (size_t)BATCH * 1024 * 32;
  constexpr size_t NEED1 = 1024 + BLOBS + SC1 * 8;
  constexpr size_t NEED2 = NEED1 + UBB;
  const int mode = (ws_size >= NEED2) ? 2 : (ws_size >= NEED1 ? 1 : 0);

  char* base = (char*)d_ws;
  int* flag = (int*)base;
  short* ABb = (short*)(base + 1024);
  short* EFb = ABb + (size_t)512 * 4096;
  short* CDb = EFb + (size_t)512 * 4096;
  short* Gb = CDb + (size_t)512 * 1024;
  float* Sc = (mode >= 1) ? (float*)(Gb + (size_t)512 * 1024) : (float*)(base + 1024);
  float* Sa = Sc + SC1;
  short* Ub = (short*)(Sa + SC1);

  k_detect<<<1, 64, 0, stream>>>((const unsigned short*)U, flag);
  if (mode >= 1) {
    k_prep<0><<<512, 256, 0, stream>>>(flag, A, B, C, D, E, F, G, ABb, EFb, CDb, Gb);
    k_prep<1><<<512, 256, 0, stream>>>(flag, A, B, C, D, E, F, G, ABb, EFb, CDb, Gb);
  }
  if (mode == 2) k_prepU<<<16384, 256, 0, stream>>>(flag, (const float*)U, Ub);

  if (mode >= 1) {
    k1_scan<0, 1><<<dim3(NCH, 65), 256, 0, stream>>>(flag, U, A, B, E, F, ABb, EFb, Ub, Sc, Sa);
    if (mode == 2)
      k1_scan<1, 2><<<dim3(NCH, 65), 256, 0, stream>>>(flag, U, A, B, E, F, ABb, EFb, Ub, Sc, Sa);
    else
      k1_scan<1, 1><<<dim3(NCH, 65), 256, 0, stream>>>(flag, U, A, B, E, F, ABb, EFb, Ub, Sc, Sa);
    k2_comb<<<dim3(BATCH / 8, 2), 256, 0, stream>>>(Sc, Sa);
    k3_merged<0, 1><<<dim3(NCH, 64), 256, 0, stream>>>(flag, U, bias, ABb, EFb, CDb, Gb, Ub,
                                                       Sc, Sa, d_out);
    if (mode == 2)
      k3_merged<1, 2><<<dim3(NCH, 64), 256, 0, stream>>>(flag, U, bias, ABb, EFb, CDb, Gb, Ub,
                                                         Sc, Sa, d_out);
    else
      k3_merged<1, 1><<<dim3(NCH, 64), 256, 0, stream>>>(flag, U, bias, ABb, EFb, CDb, Gb, Ub,
                                                         Sc, Sa, d_out);
  } else {
    k1_scan<0, 0><<<dim3(NCH, 65), 256, 0, stream>>>(flag, U, A, B, E, F, ABb, EFb, Ub, Sc, Sa);
    k1_scan<1, 0><<<dim3(NCH, 65), 256, 0, stream>>>(flag, U, A, B, E, F, ABb, EFb, Ub, Sc, Sa);
    k2_comb<<<dim3(BATCH / 8, 2), 256, 0, stream>>>(Sc, Sa);
    k3_legacy<0><<<dim3(NCH, 64), 256, 0, stream>>>(flag, U, A, B, C, D, E, F, G, bias,
                                                    Sc, Sa, d_out);
    k3_legacy<1><<<dim3(NCH, 64), 256, 0, stream>>>(flag, U, A, B, C, D, E, F, G, bias,
                                                    Sc, Sa, d_out);
  }
}